// Round 7
// baseline (365.169 us; speedup 1.0000x reference)
//
#include <hip/hip_runtime.h>
#include <cstddef>
#include <cstdint>

#define HIDDEN    1024
#define OUTD      1024
#define NUM_TABLE 64
#define CODE_LEN  10
#define TABLE_SZ  1024
#define TOTAL_DIM 640

#define TAU   1e-3f
#define FCAP  65536u

typedef float  fx4    __attribute__((ext_vector_type(4)));
typedef ushort ux4    __attribute__((ext_vector_type(4)));
typedef ushort ux8    __attribute__((ext_vector_type(8)));
typedef short  bf16x8 __attribute__((ext_vector_type(8)));
typedef float  f32x4  __attribute__((ext_vector_type(4)));

// ---------- bf16 helpers (truncation split: v = hi + lo + O(2^-16 v)) ----------
struct bfp { ushort hi, lo; };
static __device__ __forceinline__ bfp split2(float v) {
    uint32_t u  = __float_as_uint(v);
    float    fh = __uint_as_float(u & 0xFFFF0000u);
    uint32_t ul = __float_as_uint(v - fh);   // exact subtraction
    bfp r; r.hi = (ushort)(u >> 16); r.lo = (ushort)(ul >> 16);
    return r;
}
static __device__ __forceinline__ ushort f2bf(float f) {   // RNE, for tables
    uint32_t u = __float_as_uint(f);
    return (ushort)((u + 0x7FFFu + ((u >> 16) & 1u)) >> 16);
}

// ---------------- split + transpose W: [1024][640] f32 -> wht/wlt [640][1024] bf16 ----
__global__ __launch_bounds__(256)
void split_wt(const float* __restrict__ W, ushort* __restrict__ wht, ushort* __restrict__ wlt)
{
    __shared__ float t[32][33];
    const int d0 = blockIdx.x * 32, k0 = blockIdx.y * 32;
    const int lx = threadIdx.x & 31, ly = threadIdx.x >> 5;   // 32 x 8
    #pragma unroll
    for (int i = 0; i < 32; i += 8)
        t[ly + i][lx] = W[(size_t)(k0 + ly + i) * TOTAL_DIM + d0 + lx];
    __syncthreads();
    #pragma unroll
    for (int i = 0; i < 32; i += 8) {
        bfp s = split2(t[lx][ly + i]);        // = W[k0+lx][d0+ly+i]
        size_t o = (size_t)(d0 + ly + i) * HIDDEN + k0 + lx;
        wht[o] = s.hi; wlt[o] = s.lo;
    }
}

// ---------------- fused: MFMA GEMM (blocks < GEMM_BLKS) + table convert (rest) ----
// GEMM: z = x @ W + b via bf16x3. 128x128 tile, BK=32, 4 waves (2x2), 4x4 frags.
// Convert: fp32 tables -> bf16, split into two 512-col halves btabA/btabB.
#define GBM 128
#define GBN 128
#define GBK 32
#define LDK 40        // padded inner dim (80 B row stride)
#define GEMM_MB (8192 / GBM)          // 64
#define GEMM_NB (TOTAL_DIM / GBN)     // 5
#define GEMM_BLKS (GEMM_MB * GEMM_NB) // 320
#define CONV_BLKS 1024

__global__ __launch_bounds__(256)
void gemm_convert(const float* __restrict__ x, const ushort* __restrict__ wht,
                  const ushort* __restrict__ wlt, const float* __restrict__ bproj,
                  float* __restrict__ z,
                  const float* __restrict__ tables,
                  ushort* __restrict__ btabA, ushort* __restrict__ btabB)
{
    __shared__ ushort Ah[GBM][LDK];
    __shared__ ushort Al[GBM][LDK];
    __shared__ ushort Bh[GBN][LDK];
    __shared__ ushort Bl[GBN][LDK];

    const int gb  = blockIdx.x;
    const int tid = threadIdx.x;

    if (gb >= GEMM_BLKS) {
        // ---- convert path: grid-stride over 16.78M float4s, nt loads ----
        const int n4 = NUM_TABLE * TABLE_SZ * (OUTD / 4);     // 16,777,216
        const fx4* tp = (const fx4*)tables;
        const int stride = CONV_BLKS * 256;
        for (int i = (gb - GEMM_BLKS) * 256 + tid; i < n4; i += stride) {
            fx4 v = __builtin_nontemporal_load(&tp[i]);
            ux4 u;
            u.x = f2bf(v.x); u.y = f2bf(v.y); u.z = f2bf(v.z); u.w = f2bf(v.w);
            int row = i >> 8;            // 256 float4 per 1024-col row
            int cg  = i & 255;           // col group (4 cols)
            if (cg < 128) *(ux4*)&btabA[(size_t)row * 512 + cg * 4]         = u;
            else          *(ux4*)&btabB[(size_t)row * 512 + (cg - 128) * 4] = u;
        }
        return;
    }

    // ---- GEMM path ----
    const int lane = tid & 63, wid = tid >> 6;
    const int wr = wid >> 1, wc = wid & 1;           // 2x2 wave grid
    const int brow = (gb % GEMM_MB) * GBM;
    const int bcol = (gb / GEMM_MB) * GBN;
    const int fr = lane & 15, fq = lane >> 4;

    f32x4 acc[4][4] = {};

    for (int k0 = 0; k0 < HIDDEN; k0 += GBK) {
        #pragma unroll
        for (int i = 0; i < 4; ++i) {
            int c = tid + i * 256;                   // 0..1023
            int r = c >> 3, kc = (c & 7) * 4;
            fx4 v = *(const fx4*)&x[(size_t)(brow + r) * HIDDEN + k0 + kc];
            bfp s0 = split2(v.x), s1 = split2(v.y), s2 = split2(v.z), s3 = split2(v.w);
            ux4 h, l;
            h.x = s0.hi; l.x = s0.lo;
            h.y = s1.hi; l.y = s1.lo;
            h.z = s2.hi; l.z = s2.lo;
            h.w = s3.hi; l.w = s3.lo;
            *(ux4*)&Ah[r][kc] = h;
            *(ux4*)&Al[r][kc] = l;
        }
        #pragma unroll
        for (int i = 0; i < 2; ++i) {
            int c = tid + i * 256;                   // 0..511
            int nr = c >> 2, kc = (c & 3) * 8;
            size_t o = (size_t)(bcol + nr) * HIDDEN + k0 + kc;
            *(ux8*)&Bh[nr][kc] = *(const ux8*)&wht[o];
            *(ux8*)&Bl[nr][kc] = *(const ux8*)&wlt[o];
        }
        __syncthreads();

        bf16x8 ah[4], al[4], bh[4], bl[4];
        #pragma unroll
        for (int m = 0; m < 4; ++m) {
            ah[m] = *(const bf16x8*)&Ah[wr * 64 + m * 16 + fr][fq * 8];
            al[m] = *(const bf16x8*)&Al[wr * 64 + m * 16 + fr][fq * 8];
        }
        #pragma unroll
        for (int n = 0; n < 4; ++n) {
            bh[n] = *(const bf16x8*)&Bh[wc * 64 + n * 16 + fr][fq * 8];
            bl[n] = *(const bf16x8*)&Bl[wc * 64 + n * 16 + fr][fq * 8];
        }
        #pragma unroll
        for (int m = 0; m < 4; ++m)
            #pragma unroll
            for (int n = 0; n < 4; ++n) {
                acc[m][n] = __builtin_amdgcn_mfma_f32_16x16x32_bf16(ah[m], bh[n], acc[m][n], 0, 0, 0);
                acc[m][n] = __builtin_amdgcn_mfma_f32_16x16x32_bf16(ah[m], bl[n], acc[m][n], 0, 0, 0);
                acc[m][n] = __builtin_amdgcn_mfma_f32_16x16x32_bf16(al[m], bh[n], acc[m][n], 0, 0, 0);
            }
        __syncthreads();
    }

    // epilogue: C/D mapping col=lane&15, row=(lane>>4)*4+reg
    #pragma unroll
    for (int n = 0; n < 4; ++n) {
        int col = bcol + wc * 64 + n * 16 + fr;
        float bb = bproj[col];
        #pragma unroll
        for (int m = 0; m < 4; ++m) {
            int rbase = brow + wr * 64 + m * 16 + fq * 4;
            #pragma unroll
            for (int j = 0; j < 4; ++j)
                z[(size_t)(rbase + j) * TOTAL_DIM + col] = acc[m][n][j] + bb;
        }
    }
}

// ---------------- code / score + near-zero flagging ----------------
__global__ __launch_bounds__(256)
void code_score2(const float* __restrict__ z, int* __restrict__ code,
                 float* __restrict__ score, uint32_t* __restrict__ flags,
                 uint32_t* __restrict__ cnt, int NT)
{
    int idx = blockIdx.x * 256 + threadIdx.x;
    if (idx >= NT) return;
    int n = idx >> 6;
    int t = idx & 63;
    const float* zp = z + (size_t)n * TOTAL_DIM + t * CODE_LEN;
    float s = 1.0f;
    int   c = 0;
    #pragma unroll
    for (int i = 0; i < CODE_LEN; ++i) {
        float v = zp[i];
        if (fabsf(v) < TAU) {                       // sign uncertain under bf16x3
            uint32_t slot = atomicAdd(cnt, 1u);
            if (slot < FCAP) flags[slot] = (uint32_t)(n * TOTAL_DIM + t * CODE_LEN + i);
        }
        s *= 0.5f * (1.0f + tanhf(fabsf(v)));
        c |= (v > 0.0f) ? (1 << i) : 0;
    }
    code[idx]  = c;
    score[idx] = s;
}

// ---------------- exact fp32 recompute of flagged z; fix code bits ----------------
__global__ __launch_bounds__(256)
void fixz(const float* __restrict__ x, const float* __restrict__ W,
          const float* __restrict__ bproj, const float* __restrict__ z,
          int* __restrict__ code, const uint32_t* __restrict__ flags,
          const uint32_t* __restrict__ cnt)
{
    const int lane = threadIdx.x & 63;
    const int gw   = (blockIdx.x * 256 + threadIdx.x) >> 6;
    const int nw   = (gridDim.x * 256) >> 6;
    uint32_t count = *cnt;
    if (count > FCAP) count = FCAP;

    for (uint32_t f = gw; f < count; f += nw) {
        uint32_t e = flags[f];
        int n = e / TOTAL_DIM, d = e % TOTAL_DIM;
        const float* xr = x + (size_t)n * HIDDEN;
        float p = 0.0f;
        #pragma unroll
        for (int j = 0; j < 16; ++j) {
            int k = lane + j * 64;
            p = fmaf(xr[k], W[(size_t)k * TOTAL_DIM + d], p);
        }
        #pragma unroll
        for (int off = 32; off; off >>= 1) p += __shfl_xor(p, off);
        float v = p + bproj[d];
        if (lane == 0) {
            float vold = z[e];
            if ((v > 0.0f) != (vold > 0.0f)) {
                int t = d / CODE_LEN, i = d % CODE_LEN;
                atomicXor(&code[n * NUM_TABLE + t], 1 << i);
            }
        }
    }
}

// ---------------- gather + weighted sum over one 512-col half ----------------
// 128 threads x float4 cols; btabH is [64K rows][512] bf16 contiguous (67 MB -> L3-fit)
__global__ __launch_bounds__(128)
void gather_half(const ushort* __restrict__ btabH, const float* __restrict__ bias,
                 const int* __restrict__ code, const float* __restrict__ score,
                 float* __restrict__ out, int colbase)
{
    __shared__ int   sc[NUM_TABLE];
    __shared__ float sw[NUM_TABLE];

    const int n   = blockIdx.x;
    const int tid = threadIdx.x;

    if (tid < NUM_TABLE) {
        sc[tid] = code[n * NUM_TABLE + tid];
        sw[tid] = score[n * NUM_TABLE + tid];
    }
    __syncthreads();

    float4 acc = *(const float4*)&bias[colbase + tid * 4];

    #pragma unroll 4
    for (int t = 0; t < NUM_TABLE; ++t) {
        const ux4 v = *(const ux4*)&btabH[((size_t)(t * TABLE_SZ + sc[t])) * 512 + tid * 4];
        float w = sw[t];
        acc.x += w * __uint_as_float((uint32_t)v.x << 16);
        acc.y += w * __uint_as_float((uint32_t)v.y << 16);
        acc.z += w * __uint_as_float((uint32_t)v.z << 16);
        acc.w += w * __uint_as_float((uint32_t)v.w << 16);
    }

    *(float4*)&out[(size_t)n * OUTD + colbase + tid * 4] = acc;
}

// ---------------- fallback path (ws too small): fp32 vector GEMM + f32 gather ----
#define BM 64
#define BN 64
#define BK 32
__global__ __launch_bounds__(256)
void gemm_proj(const float* __restrict__ x, const float* __restrict__ W,
               const float* __restrict__ bproj, float* __restrict__ z)
{
    __shared__ float As[BK][BM + 4];
    __shared__ float Bs[BK][BN];
    const int tid  = threadIdx.x;
    const int brow = blockIdx.x * BM;
    const int bcol = blockIdx.y * BN;
    const int tr   = tid >> 4;
    const int tc   = tid & 15;
    float acc[4][4] = {};
    for (int k0 = 0; k0 < HIDDEN; k0 += BK) {
        #pragma unroll
        for (int i = 0; i < 2; ++i) {
            int lin = tid + i * 256;
            int r = lin >> 3, c8 = lin & 7;
            float4 a = *(const float4*)&x[(size_t)(brow + r) * HIDDEN + k0 + c8 * 4];
            As[c8 * 4 + 0][r] = a.x; As[c8 * 4 + 1][r] = a.y;
            As[c8 * 4 + 2][r] = a.z; As[c8 * 4 + 3][r] = a.w;
        }
        #pragma unroll
        for (int i = 0; i < 2; ++i) {
            int lin = tid + i * 256;
            int kk = lin >> 4, m4 = lin & 15;
            *(float4*)&Bs[kk][m4 * 4] =
                *(const float4*)&W[(size_t)(k0 + kk) * TOTAL_DIM + bcol + m4 * 4];
        }
        __syncthreads();
        #pragma unroll
        for (int kk = 0; kk < BK; ++kk) {
            float4 a = *(const float4*)&As[kk][tr * 4];
            float4 b = *(const float4*)&Bs[kk][tc * 4];
            acc[0][0] += a.x * b.x; acc[0][1] += a.x * b.y; acc[0][2] += a.x * b.z; acc[0][3] += a.x * b.w;
            acc[1][0] += a.y * b.x; acc[1][1] += a.y * b.y; acc[1][2] += a.y * b.z; acc[1][3] += a.y * b.w;
            acc[2][0] += a.z * b.x; acc[2][1] += a.z * b.y; acc[2][2] += a.z * b.z; acc[2][3] += a.z * b.w;
            acc[3][0] += a.w * b.x; acc[3][1] += a.w * b.y; acc[3][2] += a.w * b.z; acc[3][3] += a.w * b.w;
        }
        __syncthreads();
    }
    float4 bb = *(const float4*)&bproj[bcol + tc * 4];
    #pragma unroll
    for (int i = 0; i < 4; ++i) {
        int r = brow + tr * 4 + i;
        float4 o = {acc[i][0] + bb.x, acc[i][1] + bb.y, acc[i][2] + bb.z, acc[i][3] + bb.w};
        *(float4*)&z[(size_t)r * TOTAL_DIM + bcol + tc * 4] = o;
    }
}

__global__ __launch_bounds__(256)
void code_score(const float* __restrict__ z, int* __restrict__ code,
                float* __restrict__ score, int NT)
{
    int idx = blockIdx.x * 256 + threadIdx.x;
    if (idx >= NT) return;
    int n = idx >> 6, t = idx & 63;
    const float* zp = z + (size_t)n * TOTAL_DIM + t * CODE_LEN;
    float s = 1.0f; int c = 0;
    #pragma unroll
    for (int i = 0; i < CODE_LEN; ++i) {
        float v = zp[i];
        s *= 0.5f * (1.0f + tanhf(fabsf(v)));
        c |= (v > 0.0f) ? (1 << i) : 0;
    }
    code[idx] = c; score[idx] = s;
}

__global__ __launch_bounds__(256)
void gather_sum_f32(const float* __restrict__ tables, const float* __restrict__ bias,
                    const int* __restrict__ code, const float* __restrict__ score,
                    float* __restrict__ out)
{
    __shared__ int   sc[NUM_TABLE];
    __shared__ float sw[NUM_TABLE];
    const int n = blockIdx.x, tid = threadIdx.x;
    if (tid < NUM_TABLE) {
        sc[tid] = code[n * NUM_TABLE + tid];
        sw[tid] = score[n * NUM_TABLE + tid];
    }
    __syncthreads();
    float4 acc = *(const float4*)&bias[tid * 4];
    #pragma unroll 4
    for (int t = 0; t < NUM_TABLE; ++t) {
        const float* row = tables + ((size_t)(t * TABLE_SZ + sc[t])) * OUTD;
        float4 v = *(const float4*)&row[tid * 4];
        float w = sw[t];
        acc.x += v.x * w; acc.y += v.y * w; acc.z += v.z * w; acc.w += v.w * w;
    }
    *(float4*)&out[(size_t)n * OUTD + tid * 4] = acc;
}

extern "C" void kernel_launch(void* const* d_in, const int* in_sizes, int n_in,
                              void* d_out, int out_size, void* d_ws, size_t ws_size,
                              hipStream_t stream) {
    const float* x      = (const float*)d_in[0];
    const float* W      = (const float*)d_in[1];
    const float* bproj  = (const float*)d_in[2];
    const float* tables = (const float*)d_in[3];
    const float* bias   = (const float*)d_in[4];
    float* out = (float*)d_out;

    const int N = in_sizes[0] / HIDDEN;           // 8192

    // ws: z | code | score | wht | wlt | flags | cnt | btabA | btabB
    char* ws = (char*)d_ws;
    size_t off_z     = 0;
    size_t off_code  = off_z     + (size_t)N * TOTAL_DIM * sizeof(float);
    size_t off_score = off_code  + (size_t)N * NUM_TABLE * sizeof(int);
    size_t off_wht   = off_score + (size_t)N * NUM_TABLE * sizeof(float);
    size_t off_wlt   = off_wht   + (size_t)TOTAL_DIM * HIDDEN * sizeof(ushort);
    size_t off_flags = off_wlt   + (size_t)TOTAL_DIM * HIDDEN * sizeof(ushort);
    size_t off_cnt   = off_flags + (size_t)FCAP * sizeof(uint32_t);
    size_t off_btabA = (off_cnt + 4 + 255) & ~(size_t)255;
    size_t half_b    = (size_t)NUM_TABLE * TABLE_SZ * 512 * sizeof(ushort);  // 67.1 MB
    size_t off_btabB = off_btabA + half_b;
    size_t need      = off_btabB + half_b;

    float*    z     = (float*)(ws + off_z);
    int*      code  = (int*)(ws + off_code);
    float*    score = (float*)(ws + off_score);
    ushort*   wht   = (ushort*)(ws + off_wht);
    ushort*   wlt   = (ushort*)(ws + off_wlt);
    uint32_t* flags = (uint32_t*)(ws + off_flags);
    uint32_t* cnt   = (uint32_t*)(ws + off_cnt);
    ushort*   btabA = (ushort*)(ws + off_btabA);
    ushort*   btabB = (ushort*)(ws + off_btabB);

    int NT = N * NUM_TABLE;

    if (ws_size >= need) {
        dim3 gw(TOTAL_DIM / 32, HIDDEN / 32);
        split_wt<<<gw, 256, 0, stream>>>(W, wht, wlt);
        (void)hipMemsetAsync(cnt, 0, 4, stream);

        gemm_convert<<<GEMM_BLKS + CONV_BLKS, 256, 0, stream>>>(
            x, wht, wlt, bproj, z, tables, btabA, btabB);

        code_score2<<<(NT + 255) / 256, 256, 0, stream>>>(z, code, score, flags, cnt, NT);
        fixz<<<512, 256, 0, stream>>>(x, W, bproj, z, code, flags, cnt);

        gather_half<<<N, 128, 0, stream>>>(btabA, bias, code, score, out, 0);
        gather_half<<<N, 128, 0, stream>>>(btabB, bias, code, score, out, 512);
    } else {
        dim3 g1(N / BM, TOTAL_DIM / BN);
        gemm_proj<<<g1, 256, 0, stream>>>(x, W, bproj, z);
        code_score<<<(NT + 255) / 256, 256, 0, stream>>>(z, code, score, NT);
        gather_sum_f32<<<N, 256, 0, stream>>>(tables, bias, code, score, out);
    }
}